// Round 1
// baseline (48.821 us; speedup 1.0000x reference)
//
#include <hip/hip_runtime.h>

// out = (Q K^T) V  ==  Q (K^T V)   [no softmax -> linear -> reassociate]
// B=2,H=8,S=4096,D=64 fp32. 16 head-slices of [4096,64].
//
// K1: part[g][d][e] = sum_{k in 128-row chunk} K[k][e]*V[k][d]   (fp32)
// K2: Mt[h][d][e]   = sum_c part[h*32+c][d][e]  -> bf16          (128 KB)
// K3: out[i][d]     = sum_e Q[i][e]*M[e][d]  via mfma_32x32x16_bf16

#define SD 262144  // S*D
#define SDIM 4096
#define DDIM 64
#define NH 16      // B*H
#define NCHUNK 32
#define CHUNK 128  // SDIM / NCHUNK

typedef short bf16x8 __attribute__((ext_vector_type(8)));
typedef float f32x16 __attribute__((ext_vector_type(16)));

__device__ __forceinline__ unsigned short f2bf(float f) {
    unsigned int u = __float_as_uint(f);
    u += 0x7fffu + ((u >> 16) & 1u);   // round-to-nearest-even
    return (unsigned short)(u >> 16);
}

// ---------------- K1: partial K^T V over a 128-row chunk ----------------
// thread: e = t&63 (lane, coalesced K loads), dg = t>>6 (wave id, 16 d's).
__global__ __launch_bounds__(256) void ktv_partial(const float* __restrict__ Kp,
                                                   const float* __restrict__ Vp,
                                                   float* __restrict__ part) {
    const int g = blockIdx.x;      // [0, NH*NCHUNK)
    const int h = g >> 5;
    const int c = g & 31;
    const float* Kh = Kp + (size_t)h * SD + (size_t)c * CHUNK * DDIM;
    const float* Vh = Vp + (size_t)h * SD + (size_t)c * CHUNK * DDIM;
    const int t = threadIdx.x;
    const int e = t & 63;
    const int dg = t >> 6;         // 0..3

    float acc[16];
#pragma unroll
    for (int j = 0; j < 16; ++j) acc[j] = 0.f;

#pragma unroll 4
    for (int kk = 0; kk < CHUNK; ++kk) {
        const float kv = Kh[kk * DDIM + e];                       // coalesced
        const float4* vr = (const float4*)(Vh + kk * DDIM + dg * 16);  // wave-uniform
        const float4 v0 = vr[0], v1 = vr[1], v2 = vr[2], v3 = vr[3];
        acc[0]  += kv * v0.x;  acc[1]  += kv * v0.y;
        acc[2]  += kv * v0.z;  acc[3]  += kv * v0.w;
        acc[4]  += kv * v1.x;  acc[5]  += kv * v1.y;
        acc[6]  += kv * v1.z;  acc[7]  += kv * v1.w;
        acc[8]  += kv * v2.x;  acc[9]  += kv * v2.y;
        acc[10] += kv * v2.z;  acc[11] += kv * v2.w;
        acc[12] += kv * v3.x;  acc[13] += kv * v3.y;
        acc[14] += kv * v3.z;  acc[15] += kv * v3.w;
    }
    // part layout: [g][d][e] -> coalesced over e
    float* pg = part + (size_t)g * 4096;
#pragma unroll
    for (int j = 0; j < 16; ++j) pg[(dg * 16 + j) * 64 + e] = acc[j];
}

// ---------------- K2: reduce 32 partials -> Mt bf16 [h][d][e] ----------------
__global__ __launch_bounds__(256) void reduce_mt(const float* __restrict__ part,
                                                 unsigned short* __restrict__ mt) {
    const int b = blockIdx.x;      // [0,256)
    const int h = b >> 4;
    const int d = (b & 15) * 4 + (threadIdx.x >> 6);
    const int e = threadIdx.x & 63;
    const float* ph = part + (size_t)h * NCHUNK * 4096 + d * 64 + e;
    float s = 0.f;
#pragma unroll
    for (int c = 0; c < NCHUNK; ++c) s += ph[(size_t)c * 4096];
    mt[(size_t)h * 4096 + d * 64 + e] = f2bf(s);
}

// ---------------- K3: out = Q @ M via MFMA 32x32x16 bf16 ----------------
// block = 4 waves; wave w owns 32 q-rows x 64 d. No LDS, no barrier.
// A-frag: lane holds Q[row=l&31][k=(l>>5)*8+j]  (8 consecutive fp32 -> bf16)
// B-frag: lane holds M[k=e][col=d] = Mt[d][e]   (8 consecutive bf16 = 16B)
// C/D:    col = l&31, row = (r&3) + 8*(r>>2) + 4*(l>>5)   [HW-verified]
__global__ __launch_bounds__(256) void qm_gemm(const float* __restrict__ Qp,
                                               const unsigned short* __restrict__ mt,
                                               float* __restrict__ out) {
    const int bx = blockIdx.x;     // [0, NH*32)
    const int h = bx >> 5;
    const int qt = bx & 31;        // 128-row tile
    const int w = threadIdx.x >> 6;
    const int l = threadIdx.x & 63;
    const int l31 = l & 31;
    const int kg = (l >> 5) * 8;

    const float* Qh = Qp + (size_t)h * SD + (size_t)(qt * 128 + w * 32) * DDIM;
    const unsigned short* Mh = mt + (size_t)h * 4096;

    bf16x8 a[4];
#pragma unroll
    for (int kk = 0; kk < 4; ++kk) {
        const float4* q4 = (const float4*)(Qh + (size_t)l31 * DDIM + kk * 16 + kg);
        const float4 q0 = q4[0], q1 = q4[1];
        bf16x8 av;
        av[0] = (short)f2bf(q0.x); av[1] = (short)f2bf(q0.y);
        av[2] = (short)f2bf(q0.z); av[3] = (short)f2bf(q0.w);
        av[4] = (short)f2bf(q1.x); av[5] = (short)f2bf(q1.y);
        av[6] = (short)f2bf(q1.z); av[7] = (short)f2bf(q1.w);
        a[kk] = av;
    }

    f32x16 acc0 = {};
    f32x16 acc1 = {};
#pragma unroll
    for (int kk = 0; kk < 4; ++kk) {
        const bf16x8 b0 = *(const bf16x8*)(Mh + (size_t)l31 * 64 + kk * 16 + kg);
        const bf16x8 b1 = *(const bf16x8*)(Mh + (size_t)(l31 + 32) * 64 + kk * 16 + kg);
        acc0 = __builtin_amdgcn_mfma_f32_32x32x16_bf16(a[kk], b0, acc0, 0, 0, 0);
        acc1 = __builtin_amdgcn_mfma_f32_32x32x16_bf16(a[kk], b1, acc1, 0, 0, 0);
    }

    float* Oh = out + (size_t)h * SD + (size_t)(qt * 128 + w * 32) * DDIM;
#pragma unroll
    for (int r = 0; r < 16; ++r) {
        const int row = (r & 3) + 8 * (r >> 2) + 4 * (l >> 5);
        Oh[(size_t)row * DDIM + l31] = acc0[r];
        Oh[(size_t)row * DDIM + 32 + l31] = acc1[r];
    }
}

extern "C" void kernel_launch(void* const* d_in, const int* in_sizes, int n_in,
                              void* d_out, int out_size, void* d_ws, size_t ws_size,
                              hipStream_t stream) {
    const float* q = (const float*)d_in[0];
    const float* k = (const float*)d_in[1];
    const float* v = (const float*)d_in[2];
    float* out = (float*)d_out;

    float* part = (float*)d_ws;                                       // 8 MB
    unsigned short* mt =
        (unsigned short*)((char*)d_ws + (size_t)NH * NCHUNK * 4096 * 4);  // 128 KB

    ktv_partial<<<NH * NCHUNK, 256, 0, stream>>>(k, v, part);
    reduce_mt<<<256, 256, 0, stream>>>(part, mt);
    qm_gemm<<<NH * 32, 256, 0, stream>>>(q, mt, out);
}

// Round 2
// 23.350 us; speedup vs baseline: 2.0908x; 2.0908x over previous
//
#include <hip/hip_runtime.h>

// out = (Q K^T) V  ==  Q (K^T V)   [no softmax -> linear -> reassociate]
// B=2,H=8,S=4096,D=64 fp32. 16 head-slices of [4096,64].
//
// K1: part[g][d][e] = sum_{s in 128-row chunk} V[s][d]*K[s][e]  via MFMA
//     (computes M^T = V^T K directly so output layout matches K2/K3)
// K2: Mt[h][d][e]   = sum_c part[h*32+c][d][e]  -> bf16          (128 KB)
// K3: out[i][d]     = sum_e Q[i][e]*M[e][d]  via mfma_32x32x16_bf16

#define SD 262144  // S*D
#define SDIM 4096
#define DDIM 64
#define NH 16      // B*H
#define NCHUNK 32
#define CHUNK 128  // SDIM / NCHUNK

typedef short bf16x8 __attribute__((ext_vector_type(8)));
typedef float f32x16 __attribute__((ext_vector_type(16)));

__device__ __forceinline__ unsigned short f2bf(float f) {
    unsigned int u = __float_as_uint(f);
    u += 0x7fffu + ((u >> 16) & 1u);   // round-to-nearest-even
    return (unsigned short)(u >> 16);
}

// ---------------- K1: partial V^T K over a 128-row chunk (MFMA) ----------------
// 4 waves/block; wave w owns quadrant (dh, eh) = ((w>>1)*32, (w&1)*32) of the
// 64x64 partial M^T. Fragment pattern identical to K3 (verified):
//   A-frag: lane holds A[row=l31][k=kg+j] with A=V^T  -> V[s0+kg+j][dh+l31]
//   B-frag: lane holds B[k=kg+j][col=l31] with B=K    -> K[s0+kg+j][eh+l31]
//   D[row=d][col=e]: d=(r&3)+8*(r>>2)+4*(l>>5), e=l31  -> coalesced row writes
__global__ __launch_bounds__(256) void ktv_mfma(const float* __restrict__ Kp,
                                                const float* __restrict__ Vp,
                                                float* __restrict__ part) {
    const int g = blockIdx.x;      // [0, NH*NCHUNK)
    const int h = g >> 5;
    const int c = g & 31;
    const size_t base = (size_t)h * SD + (size_t)c * CHUNK * DDIM;

    const int w = threadIdx.x >> 6;
    const int l = threadIdx.x & 63;
    const int l31 = l & 31;
    const int kg = (l >> 5) * 8;
    const int dh = (w >> 1) * 32;
    const int eh = (w & 1) * 32;

    const float* Vb = Vp + base + dh + l31;   // A operand column
    const float* Kb = Kp + base + eh + l31;   // B operand column

    f32x16 acc = {};
#pragma unroll
    for (int s0 = 0; s0 < CHUNK; s0 += 16) {
        float av[8], bv[8];
#pragma unroll
        for (int j = 0; j < 8; ++j) {
            av[j] = Vb[(size_t)(s0 + kg + j) * DDIM];
            bv[j] = Kb[(size_t)(s0 + kg + j) * DDIM];
        }
        bf16x8 afr, bfr;
#pragma unroll
        for (int j = 0; j < 8; ++j) {
            afr[j] = (short)f2bf(av[j]);
            bfr[j] = (short)f2bf(bv[j]);
        }
        acc = __builtin_amdgcn_mfma_f32_32x32x16_bf16(afr, bfr, acc, 0, 0, 0);
    }

    float* pg = part + (size_t)g * 4096;
#pragma unroll
    for (int r = 0; r < 16; ++r) {
        const int d = (r & 3) + 8 * (r >> 2) + 4 * (l >> 5) + dh;
        pg[(size_t)d * DDIM + eh + l31] = acc[r];
    }
}

// ---------------- K2: reduce 32 partials -> Mt bf16 [h][d][e] ----------------
__global__ __launch_bounds__(256) void reduce_mt(const float* __restrict__ part,
                                                 unsigned short* __restrict__ mt) {
    const int b = blockIdx.x;      // [0,256)
    const int h = b >> 4;
    const int d = (b & 15) * 4 + (threadIdx.x >> 6);
    const int e = threadIdx.x & 63;
    const float* ph = part + (size_t)h * NCHUNK * 4096 + d * 64 + e;
    float s = 0.f;
#pragma unroll
    for (int c = 0; c < NCHUNK; ++c) s += ph[(size_t)c * 4096];
    mt[(size_t)h * 4096 + d * 64 + e] = f2bf(s);
}

// ---------------- K3: out = Q @ M via MFMA 32x32x16 bf16 ----------------
// block = 4 waves; wave w owns 32 q-rows x 64 d. No LDS, no barrier.
// A-frag: lane holds Q[row=l&31][k=(l>>5)*8+j]  (8 consecutive fp32 -> bf16)
// B-frag: lane holds M[k=e][col=d] = Mt[d][e]   (8 consecutive bf16 = 16B)
// C/D:    col = l&31, row = (r&3) + 8*(r>>2) + 4*(l>>5)   [HW-verified]
__global__ __launch_bounds__(256) void qm_gemm(const float* __restrict__ Qp,
                                               const unsigned short* __restrict__ mt,
                                               float* __restrict__ out) {
    const int bx = blockIdx.x;     // [0, NH*32)
    const int h = bx >> 5;
    const int qt = bx & 31;        // 128-row tile
    const int w = threadIdx.x >> 6;
    const int l = threadIdx.x & 63;
    const int l31 = l & 31;
    const int kg = (l >> 5) * 8;

    const float* Qh = Qp + (size_t)h * SD + (size_t)(qt * 128 + w * 32) * DDIM;
    const unsigned short* Mh = mt + (size_t)h * 4096;

    bf16x8 a[4];
#pragma unroll
    for (int kk = 0; kk < 4; ++kk) {
        const float4* q4 = (const float4*)(Qh + (size_t)l31 * DDIM + kk * 16 + kg);
        const float4 q0 = q4[0], q1 = q4[1];
        bf16x8 av;
        av[0] = (short)f2bf(q0.x); av[1] = (short)f2bf(q0.y);
        av[2] = (short)f2bf(q0.z); av[3] = (short)f2bf(q0.w);
        av[4] = (short)f2bf(q1.x); av[5] = (short)f2bf(q1.y);
        av[6] = (short)f2bf(q1.z); av[7] = (short)f2bf(q1.w);
        a[kk] = av;
    }

    f32x16 acc0 = {};
    f32x16 acc1 = {};
#pragma unroll
    for (int kk = 0; kk < 4; ++kk) {
        const bf16x8 b0 = *(const bf16x8*)(Mh + (size_t)l31 * 64 + kk * 16 + kg);
        const bf16x8 b1 = *(const bf16x8*)(Mh + (size_t)(l31 + 32) * 64 + kk * 16 + kg);
        acc0 = __builtin_amdgcn_mfma_f32_32x32x16_bf16(a[kk], b0, acc0, 0, 0, 0);
        acc1 = __builtin_amdgcn_mfma_f32_32x32x16_bf16(a[kk], b1, acc1, 0, 0, 0);
    }

    float* Oh = out + (size_t)h * SD + (size_t)(qt * 128 + w * 32) * DDIM;
#pragma unroll
    for (int r = 0; r < 16; ++r) {
        const int row = (r & 3) + 8 * (r >> 2) + 4 * (l >> 5);
        Oh[(size_t)row * DDIM + l31] = acc0[r];
        Oh[(size_t)row * DDIM + 32 + l31] = acc1[r];
    }
}

extern "C" void kernel_launch(void* const* d_in, const int* in_sizes, int n_in,
                              void* d_out, int out_size, void* d_ws, size_t ws_size,
                              hipStream_t stream) {
    const float* q = (const float*)d_in[0];
    const float* k = (const float*)d_in[1];
    const float* v = (const float*)d_in[2];
    float* out = (float*)d_out;

    float* part = (float*)d_ws;                                       // 8 MB
    unsigned short* mt =
        (unsigned short*)((char*)d_ws + (size_t)NH * NCHUNK * 4096 * 4);  // 128 KB

    ktv_mfma<<<NH * NCHUNK, 256, 0, stream>>>(k, v, part);
    reduce_mt<<<256, 256, 0, stream>>>(part, mt);
    qm_gemm<<<NH * 32, 256, 0, stream>>>(q, mt, out);
}